// Round 5
// baseline (3626.062 us; speedup 1.0000x reference)
//
#include <hip/hip_runtime.h>
#include <math.h>

#define BB 4
#define CC 64
#define NN 8192
#define OO 128
#define KK 20
#define NCH 8
#define CHSZ (NN / NCH)   // 1024
#define DD 128            // 2*CC

typedef unsigned short ushort_t;

// ---------------------------------------------------------------------------
// prep: VERBATIM round-1 (passed): xt[b][n][c] transpose + fp32 serial xx.
// ---------------------------------------------------------------------------
__global__ __launch_bounds__(128) void prep_kernel(const float* __restrict__ x,
                                                   float* __restrict__ xt,
                                                   float* __restrict__ xx) {
  __shared__ float tile[128][CC + 1];  // +1 pad: conflict-free read/write
  const int tid = threadIdx.x;
  const int b = blockIdx.y;
  const int n0 = blockIdx.x * 128;
  const float* xb = x + (size_t)b * CC * NN;
  float acc = 0.0f;
  #pragma unroll 8
  for (int c = 0; c < CC; ++c) {
    float v = xb[(size_t)c * NN + n0 + tid];   // coalesced over tid
    acc += v * v;
    tile[tid][c] = v;
  }
  xx[b * NN + n0 + tid] = acc;
  __syncthreads();
  float* xtb = xt + ((size_t)b * NN + n0) * CC;
  #pragma unroll 8
  for (int t = tid; t < 128 * CC; t += 128) {  // coalesced row writes
    xtb[t] = tile[t >> 6][t & 63];
  }
}

// ---------------------------------------------------------------------------
// knn: per (b, 64-query wave, 1024-candidate chunk). NO LDS: candidate rows
// are wave-uniform addresses -> scalar/broadcast loads from global (chunk is
// L2-resident: 1024 rows x 256 B = 256 KB). Per-pair fp32 arithmetic is
// VERBATIM round-1 (d0..d3 4-way dot, pd formula, insert/tie semantics), so
// the selected top-20 SET matches round-1's passing run. NCH=8 -> 4096
// single-wave blocks = ~16 waves/CU (round 1: 8/CU, LDS-replay-bound).
// ---------------------------------------------------------------------------
__global__ __launch_bounds__(64) void knn_kernel(const float* __restrict__ xt,
                                                 const float* __restrict__ xx,
                                                 float* __restrict__ pval,
                                                 ushort_t* __restrict__ pidx) {
  const int lane = threadIdx.x;
  const int b = blockIdx.z;
  const int ch = blockIdx.y;
  const int n = blockIdx.x * 64 + lane;
  const int m0 = ch * CHSZ;
  const float* xtb = xt + (size_t)b * NN * CC;

  float4 q[16];
  {
    const float4* qp = (const float4*)(xtb + (size_t)n * CC);
    #pragma unroll
    for (int i = 0; i < 16; ++i) q[i] = qp[i];
  }
  const float xxn = xx[b * NN + n];

  float tv[KK];
  int ti[KK];
  #pragma unroll
  for (int j = 0; j < KK; ++j) { tv[j] = -INFINITY; ti[j] = -1; }
  float minv = -INFINITY;

  #pragma unroll 2
  for (int r = 0; r < CHSZ; ++r) {
    const int mi = m0 + r;
    const float4* cp = (const float4*)(xtb + (size_t)mi * CC);  // uniform addr
    const float cxxr = xx[b * NN + mi];                          // uniform
    float d0 = 0.f, d1 = 0.f, d2 = 0.f, d3 = 0.f;                // 4-way ILP
    #pragma unroll
    for (int i = 0; i < 4; ++i) {
      float4 c0 = cp[4 * i + 0], c1 = cp[4 * i + 1];
      float4 c2 = cp[4 * i + 2], c3 = cp[4 * i + 3];
      float4 q0 = q[4 * i + 0], q1 = q[4 * i + 1];
      float4 q2 = q[4 * i + 2], q3 = q[4 * i + 3];
      d0 += q0.x * c0.x + q0.y * c0.y + q0.z * c0.z + q0.w * c0.w;
      d1 += q1.x * c1.x + q1.y * c1.y + q1.z * c1.z + q1.w * c1.w;
      d2 += q2.x * c2.x + q2.y * c2.y + q2.z * c2.z + q2.w * c2.w;
      d3 += q3.x * c3.x + q3.y * c3.y + q3.z * c3.z + q3.w * c3.w;
    }
    float dot = (d0 + d1) + (d2 + d3);
    // match reference formula: pd = -xx[n] - (-2*dot) - xx[m]
    float pd = (-xxn - (-2.0f * dot)) - cxxr;
    if (pd > minv) {
      bool done = false;
      #pragma unroll
      for (int j = 0; j < KK; ++j) {
        if (!done && tv[j] == minv) { tv[j] = pd; ti[j] = mi; done = true; }
      }
      minv = tv[0];
      #pragma unroll
      for (int j = 1; j < KK; ++j) minv = fminf(minv, tv[j]);
    }
  }

  // sort desc by value, ties asc by index (verbatim round-1 bubble)
  #pragma unroll
  for (int a = 0; a < KK - 1; ++a) {
    #pragma unroll
    for (int j = 0; j < KK - 1 - a; ++j) {
      bool sw = (tv[j + 1] > tv[j]) || (tv[j + 1] == tv[j] && ti[j + 1] < ti[j]);
      float va = sw ? tv[j + 1] : tv[j];
      float vb = sw ? tv[j] : tv[j + 1];
      int ia = sw ? ti[j + 1] : ti[j];
      int ib = sw ? ti[j] : ti[j + 1];
      tv[j] = va; tv[j + 1] = vb; ti[j] = ia; ti[j + 1] = ib;
    }
  }
  size_t base = (((size_t)b * NN + n) * NCH + ch) * KK;
  #pragma unroll
  for (int j = 0; j < KK; ++j) {
    pval[base + j] = tv[j];
    pidx[base + j] = (ushort_t)ti[j];
  }
}

// ---------------------------------------------------------------------------
// merge: per query, 8-way merge of sorted per-chunk lists -> final top-20.
// Same (value desc, index asc) rule as round 1; chunks partition ascending
// index ranges so cross-chunk exact ties resolve to the lower index.
// ---------------------------------------------------------------------------
__global__ __launch_bounds__(256) void merge_kernel(const float* __restrict__ pval,
                                                    const ushort_t* __restrict__ pidx,
                                                    int* __restrict__ fidx) {
  const int q = blockIdx.x * 256 + threadIdx.x;  // q = b*NN + n
  const float* pv = pval + (size_t)q * NCH * KK;
  const ushort_t* pi = pidx + (size_t)q * NCH * KK;
  int p[NCH];
  float v[NCH];
  int id[NCH];
  #pragma unroll
  for (int c = 0; c < NCH; ++c) {
    p[c] = 0;
    v[c] = pv[c * KK];
    id[c] = pi[c * KK];
  }
  int* fo = fidx + (size_t)q * KK;
  #pragma unroll
  for (int k = 0; k < KK; ++k) {
    float bv = v[0]; int bi = id[0]; int bc = 0;
    #pragma unroll
    for (int c = 1; c < NCH; ++c) {
      if (v[c] > bv || (v[c] == bv && id[c] < bi)) { bv = v[c]; bi = id[c]; bc = c; }
    }
    fo[k] = bi;
    #pragma unroll
    for (int c = 0; c < NCH; ++c) {
      if (bc == c) {
        ++p[c];
        v[c] = (p[c] < KK) ? pv[c * KK + p[c]] : -INFINITY;
        id[c] = (p[c] < KK) ? (int)pi[c * KK + p[c]] : 0x7fffffff;
      }
    }
  }
}

// ---------------------------------------------------------------------------
// d1: per n compute h[k][d] = y_k . W1a_d + t_d  (t_d = z.(W1b_d - W1a_d)),
// softmax over k per d, then g[d] = sum_k feats[k][d]*gate[k][d].
// VERBATIM round-1 (passed).
// ---------------------------------------------------------------------------
__global__ __launch_bounds__(256) void d1_kernel(const float* __restrict__ xt,
                                                 const float* __restrict__ W1,
                                                 const int* __restrict__ fidx,
                                                 float* __restrict__ gbuf) {
  __shared__ float w1t[DD * DD];  // [c][d] swizzled: addr = c*128 + (d ^ (c&31))
  const int tid = threadIdx.x;
  const int b = blockIdx.y;
  const int n0 = blockIdx.x * 32;
  for (int t = tid; t < DD * DD; t += 256) {
    int dd = t >> 7, c = t & 127;
    w1t[c * DD + (dd ^ (c & 31))] = W1[t];  // coalesced global read
  }
  __syncthreads();
  const int half = tid >> 7;
  const int d = tid & 127;
  const float* xtb = xt + (size_t)b * NN * CC;

  for (int i = 0; i < 16; ++i) {
    const int n = n0 + half + 2 * i;
    const int* kp = fidx + ((size_t)b * NN + n) * KK;
    int ki[KK];
    #pragma unroll
    for (int k = 0; k < KK; ++k) ki[k] = kp[k];

    float h[KK];
    #pragma unroll
    for (int k = 0; k < KK; ++k) h[k] = 0.0f;
    float td = 0.0f;
    const float4* zp = (const float4*)(xtb + (size_t)n * CC);
    for (int c4 = 0; c4 < 16; ++c4) {
      const int c = c4 * 4;
      float4 z4 = zp[c4];
      float wa0 = w1t[(c + 0) * DD + (d ^ ((c + 0) & 31))];
      float wa1 = w1t[(c + 1) * DD + (d ^ ((c + 1) & 31))];
      float wa2 = w1t[(c + 2) * DD + (d ^ ((c + 2) & 31))];
      float wa3 = w1t[(c + 3) * DD + (d ^ ((c + 3) & 31))];
      float wb0 = w1t[(c + 64) * DD + (d ^ ((c + 64) & 31))];
      float wb1 = w1t[(c + 65) * DD + (d ^ ((c + 65) & 31))];
      float wb2 = w1t[(c + 66) * DD + (d ^ ((c + 66) & 31))];
      float wb3 = w1t[(c + 67) * DD + (d ^ ((c + 67) & 31))];
      td += z4.x * (wb0 - wa0) + z4.y * (wb1 - wa1) + z4.z * (wb2 - wa2) + z4.w * (wb3 - wa3);
      #pragma unroll
      for (int k = 0; k < KK; ++k) {
        float4 y4 = *(const float4*)(xtb + (size_t)ki[k] * CC + c);  // L2-hot
        h[k] += y4.x * wa0 + y4.y * wa1 + y4.z * wa2 + y4.w * wa3;
      }
    }
    float m = h[0] + td;
    #pragma unroll
    for (int k = 0; k < KK; ++k) { h[k] += td; m = fmaxf(m, h[k]); }
    float e[KK];
    float s = 0.0f;
    #pragma unroll
    for (int k = 0; k < KK; ++k) { e[k] = expf(h[k] - m); s += e[k]; }
    const float inv = 1.0f / s;

    float g;
    if (d < 64) {  // wave-uniform branch
      const float zd = xtb[(size_t)n * CC + d];
      g = 0.0f;
      #pragma unroll
      for (int k = 0; k < KK; ++k) {
        const float yk = xtb[(size_t)ki[k] * CC + d];  // coalesced row read
        g += (yk - zd) * (e[k] * inv);
      }
    } else {
      const float zd = xtb[(size_t)n * CC + (d - 64)];
      float sg = 0.0f;
      #pragma unroll
      for (int k = 0; k < KK; ++k) sg += e[k] * inv;
      g = zd * sg;
    }
    gbuf[((size_t)b * NN + n) * DD + d] = g;
  }
}

// ---------------------------------------------------------------------------
// d2: out[b][o][n] = sum_c g[b][n][c] * W2[o][c].  VERBATIM round-1 (passed).
// ---------------------------------------------------------------------------
__global__ __launch_bounds__(256) void d2_kernel(const float* __restrict__ gbuf,
                                                 const float* __restrict__ W2,
                                                 float* __restrict__ out) {
  __shared__ float4 w2s[OO * 32];  // addr4 = o*32 + (c4 ^ (o&7))
  const int tid = threadIdx.x;
  const int b = blockIdx.y;
  const int n0 = blockIdx.x * 32;
  const float4* w2v = (const float4*)W2;
  for (int t = tid; t < OO * 32; t += 256) {
    int o = t >> 5, c4 = t & 31;
    w2s[o * 32 + (c4 ^ (o & 7))] = w2v[t];
  }
  __syncthreads();
  const int og = tid & 7;
  const int ni = tid >> 3;
  const int n = n0 + ni;
  const float4* gp = (const float4*)(gbuf + ((size_t)b * NN + n) * DD);
  float acc[16];
  #pragma unroll
  for (int j = 0; j < 16; ++j) acc[j] = 0.0f;
  for (int c4 = 0; c4 < 32; ++c4) {
    float4 g4 = gp[c4];
    #pragma unroll
    for (int j = 0; j < 16; ++j) {
      const int o = j * 8 + og;
      float4 w4 = w2s[o * 32 + (c4 ^ og)];
      acc[j] += g4.x * w4.x + g4.y * w4.y + g4.z * w4.z + g4.w * w4.w;
    }
  }
  float* outb = out + (size_t)b * OO * NN;
  #pragma unroll
  for (int j = 0; j < 16; ++j) {
    outb[(size_t)(j * 8 + og) * NN + n] = acc[j];
  }
}

// ---------------------------------------------------------------------------
// ws layout (bytes):
//   xt   @ 0          :  8,388,608
//   xx   @ 8,388,608  :    131,072
//   pval @ 8,519,680  : 20,971,520   (B*N * 8 chunks * 20 f32)
//   pidx @ 29,491,200 : 10,485,760   (u16)
//   fidx @ 39,976,960 :  2,621,440
//   gbuf @ 8,519,680  : 16,777,216   (overlays pval, dead after merge)
// total: 42,598,400 B (~40.6 MB; round 4's 45.9 MB ran fine)
// ---------------------------------------------------------------------------
extern "C" void kernel_launch(void* const* d_in, const int* in_sizes, int n_in,
                              void* d_out, int out_size, void* d_ws, size_t ws_size,
                              hipStream_t stream) {
  const float* x  = (const float*)d_in[0];
  const float* W1 = (const float*)d_in[1];
  const float* W2 = (const float*)d_in[2];
  float* out = (float*)d_out;
  char* ws = (char*)d_ws;
  float*    xt   = (float*)(ws);
  float*    xx   = (float*)(ws + 8388608);
  float*    pval = (float*)(ws + 8519680);
  ushort_t* pidx = (ushort_t*)(ws + 29491200);
  int*      fidx = (int*)(ws + 39976960);
  float*    gbuf = (float*)(ws + 8519680);

  prep_kernel<<<dim3(NN / 128, BB), 128, 0, stream>>>(x, xt, xx);
  knn_kernel<<<dim3(NN / 64, NCH, BB), 64, 0, stream>>>(xt, xx, pval, pidx);
  merge_kernel<<<dim3(BB * NN / 256), 256, 0, stream>>>(pval, pidx, fidx);
  d1_kernel<<<dim3(NN / 32, BB), 256, 0, stream>>>(xt, W1, fidx, gbuf);
  d2_kernel<<<dim3(NN / 32, BB), 256, 0, stream>>>(gbuf, W2, out);
}